// Round 8
// baseline (176.388 us; speedup 1.0000x reference)
//
#include <hip/hip_runtime.h>
#include <stdint.h>

// DiffAttention: O[n,h,d] = sum_l sigmoid(q_n.k_l) v_l / sum_l sigmoid(q_n.k_l)
// N=L=4096, H=8, M=D=64, fp32 in/out, bf16 MFMA compute.
//
// R8: barrier-free partial. R7 proved dbuf is a no-op (m99/m100 pattern):
// the loss is barrier PHASE-LOCKING (pipes used serially across lockstepped
// waves), not load latency. Fix: no LDS, no __syncthreads — K/V fragments
// load directly global->VGPR from the prepass images; per-block 16KB tile
// is L1-resident, per-XCD head working set (1MB) is L2-resident.
// K-frag and V-frag offsets share one 8-entry table:
//   off[a][c] = a*4096 + col*128 + (((c<<1)|hi)^(col&7))*16.
// V loads split in 2 batches of 4 frags to keep live VGPRs <=128
// (4 waves/SIMD; R3: never force 8 waves via launch_bounds).
// R5 lesson: no __threadfence split-K. R6: residency is register-capped.

typedef __bf16 bf16x8 __attribute__((ext_vector_type(8)));
typedef __bf16 bf16x2 __attribute__((ext_vector_type(2)));
typedef float  f32x2  __attribute__((ext_vector_type(2)));
typedef float  f32x16 __attribute__((ext_vector_type(16)));

constexpr int NH = 8, MD = 64, NL = 4096, NN = 4096;
constexpr size_t ONUM_ELEMS = (size_t)NN * NH * MD;  // per split
constexpr size_t Z_ELEMS    = (size_t)NN * NH;       // per split
constexpr size_t KB_ELEMS   = (size_t)NH * NL * MD;  // bf16
constexpr size_t VTB_ELEMS  = (size_t)NH * NL * MD;  // bf16

__device__ __forceinline__ unsigned packbf2(float a, float b) {
  bf16x2 t = __builtin_convertvector((f32x2){a, b}, bf16x2);
  return __builtin_bit_cast(unsigned, t);
}

// ---------------- prepass: one block per (h, l-tile) ----------------
__global__ __launch_bounds__(256) void diffattn_prepass(
    const float* __restrict__ Kg, const float* __restrict__ Vg,
    unsigned short* __restrict__ Kb, unsigned short* __restrict__ Vtb) {
  __shared__ __attribute__((aligned(16))) unsigned short Vt_lds[64 * 64];
  const int tid = threadIdx.x;
  const int h = blockIdx.x & 7;
  const int t = blockIdx.x >> 3;

  // ---- K: [l][h][m] fp32 -> [h][l][m] bf16, 16B chunks swizzled by l&7
#pragma unroll
  for (int e = 0; e < 2; ++e) {
    const int g = tid * 2 + e;
    const int l = g >> 3, c = g & 7;
    const float* kp = Kg + (((size_t)(t * 64 + l) * NH + h) * MD) + c * 8;
    const float4 a = *(const float4*)kp;
    const float4 b = *(const float4*)(kp + 4);
    unsigned out[4] = {packbf2(a.x, a.y), packbf2(a.z, a.w),
                       packbf2(b.x, b.y), packbf2(b.z, b.w)};
    unsigned short* dst =
        Kb + ((size_t)h * NL + t * 64 + l) * MD + ((c ^ (l & 7)) * 8);
    *(uint4*)dst = *(const uint4*)out;
  }

  // ---- V: [l][h][d] fp32 -> LDS transpose -> [h][t][d][l'] bf16,
  //      16B chunks (8 l' each) swizzled by d&7
  {
    const int lr = tid & 63, dbase = (tid >> 6) * 16;
    const float* vp = Vg + (((size_t)(t * 64 + lr) * NH + h) * MD) + dbase;
#pragma unroll
    for (int i = 0; i < 4; ++i) {
      const float4 v = *(const float4*)(vp + i * 4);
      const int d0 = dbase + i * 4;
      Vt_lds[(d0 + 0) * 64 + lr] = __builtin_bit_cast(unsigned short, (__bf16)v.x);
      Vt_lds[(d0 + 1) * 64 + lr] = __builtin_bit_cast(unsigned short, (__bf16)v.y);
      Vt_lds[(d0 + 2) * 64 + lr] = __builtin_bit_cast(unsigned short, (__bf16)v.z);
      Vt_lds[(d0 + 3) * 64 + lr] = __builtin_bit_cast(unsigned short, (__bf16)v.w);
    }
  }
  __syncthreads();
#pragma unroll
  for (int e = 0; e < 2; ++e) {
    const int g = tid * 2 + e;
    const int d = g >> 3, cl = g & 7;
    const uint4 chunk = *(const uint4*)&Vt_lds[d * 64 + cl * 8];
    unsigned short* dst = Vtb + ((size_t)(h * 64 + t) * 64 + d) * 64 +
                          ((cl ^ (d & 7)) * 8);
    *(uint4*)dst = chunk;
  }
}

// ---------------- partial (barrier-free, LDS-free) ----------------
__global__ __launch_bounds__(256, 4) void diffattn_partial(
    const float* __restrict__ Qg, const unsigned short* __restrict__ Kb,
    const unsigned short* __restrict__ Vtb, float* __restrict__ Onum,
    float* __restrict__ Zp, int nsplit, int lLen) {
  const int tid  = threadIdx.x;
  const int w    = tid >> 6;
  const int lane = tid & 63;
  const int col  = lane & 31;
  const int hi   = lane >> 5;

  const int h     = blockIdx.x & 7;
  const int tmp   = blockIdx.x >> 3;
  const int split = tmp % nsplit;
  const int n0    = (tmp / nsplit) * 128;
  const int lBeg  = split * lLen;

  // Q fragments (B operand), prescaled by -log2e: sigmoid = rcp(1+exp2(d1)).
  bf16x8 qf[4];
  {
    const float* qp = Qg + ((size_t)(n0 + w * 32 + col) * NH + h) * MD;
    const float c = -1.4426950408889634f;
#pragma unroll
    for (int kc = 0; kc < 4; ++kc) {
      const float4 x = *(const float4*)(qp + kc * 16 + hi * 8);
      const float4 y = *(const float4*)(qp + kc * 16 + hi * 8 + 4);
      bf16x8 f;
      f[0] = (__bf16)(c * x.x); f[1] = (__bf16)(c * x.y);
      f[2] = (__bf16)(c * x.z); f[3] = (__bf16)(c * x.w);
      f[4] = (__bf16)(c * y.x); f[5] = (__bf16)(c * y.y);
      f[6] = (__bf16)(c * y.z); f[7] = (__bf16)(c * y.w);
      qf[kc] = f;
    }
  }

  f32x16 oacc[2];
#pragma unroll
  for (int i = 0; i < 16; ++i) { oacc[0][i] = 0.f; oacc[1][i] = 0.f; }
  float zacc = 0.f;
  const f32x16 zf = {};  // zero C-operand for the first QK MFMA

  // Shared offset table for K and V frag loads (same pattern for both):
  //   K frag (lh,kc): kgb + off[lh][kc];  V frag (kc2,ds): vgb + off[ds][kc2]
  const int sw = col & 7;
  int off[2][4];
#pragma unroll
  for (int a = 0; a < 2; ++a)
#pragma unroll
    for (int c = 0; c < 4; ++c)
      off[a][c] = a * 4096 + col * 128 + ((((c << 1) | hi) ^ sw) * 16);

  const char* kgb = (const char*)(Kb + (size_t)h * NL * MD) + (size_t)lBeg * 128;
  const char* vgb = (const char*)(Vtb + (size_t)h * NL * MD) + (size_t)lBeg * 128;
  const int T = lLen >> 6;

  for (int t = 0; t < T; ++t) {
    // ---- QK: D1[lh] (32 l x 32 q) = K(32l x 64k) x Qscaled(64k x 32q)
    f32x16 d1[2];
#pragma unroll
    for (int lh = 0; lh < 2; ++lh) {
      const bf16x8 kf0 = *(const bf16x8*)(kgb + off[lh][0]);
      const bf16x8 kf1 = *(const bf16x8*)(kgb + off[lh][1]);
      const bf16x8 kf2 = *(const bf16x8*)(kgb + off[lh][2]);
      const bf16x8 kf3 = *(const bf16x8*)(kgb + off[lh][3]);
      d1[lh] = __builtin_amdgcn_mfma_f32_32x32x16_bf16(kf0, qf[0], zf, 0, 0, 0);
      d1[lh] = __builtin_amdgcn_mfma_f32_32x32x16_bf16(kf1, qf[1], d1[lh], 0, 0, 0);
      d1[lh] = __builtin_amdgcn_mfma_f32_32x32x16_bf16(kf2, qf[2], d1[lh], 0, 0, 0);
      d1[lh] = __builtin_amdgcn_mfma_f32_32x32x16_bf16(kf3, qf[3], d1[lh], 0, 0, 0);
    }

    // ---- V batch 1 (kc2 = 0,1), in flight during sigmoid
    bf16x8 vf[2][2];
#pragma unroll
    for (int kc2 = 0; kc2 < 2; ++kc2)
#pragma unroll
      for (int ds = 0; ds < 2; ++ds)
        vf[kc2][ds] = *(const bf16x8*)(vgb + off[ds][kc2]);

    // ---- sigmoid + Z accumulate + pack pairs (consecutive l_local) to bf16
    unsigned pk[2][8];
#pragma unroll
    for (int lh = 0; lh < 2; ++lh) {
      float s[16];
#pragma unroll
      for (int r = 0; r < 16; ++r) {
        const float e = __builtin_amdgcn_exp2f(d1[lh][r]);
        s[r] = __builtin_amdgcn_rcpf(1.0f + e);
        zacc += s[r];
      }
#pragma unroll
      for (int p = 0; p < 8; ++p) pk[lh][p] = packbf2(s[2 * p], s[2 * p + 1]);
    }

    // ---- O += P(32q x 64l) x V(64l x 64d); P A-frag via lane^32 swap
#pragma unroll
    for (int kc2 = 0; kc2 < 4; ++kc2) {
      if (kc2 == 2) {  // V batch 2 (kc2 = 2,3) reuses the vf registers
#pragma unroll
        for (int k2 = 2; k2 < 4; ++k2)
#pragma unroll
          for (int ds = 0; ds < 2; ++ds)
            vf[k2 - 2][ds] = *(const bf16x8*)(vgb + off[ds][k2]);
      }
      const int lh = kc2 >> 1, s4 = (kc2 & 1) * 4;
      const unsigned send0 = hi ? pk[lh][s4 + 0] : pk[lh][s4 + 2];
      const unsigned send1 = hi ? pk[lh][s4 + 1] : pk[lh][s4 + 3];
      const unsigned recv0 = (unsigned)__shfl_xor((int)send0, 32, 64);
      const unsigned recv1 = (unsigned)__shfl_xor((int)send1, 32, 64);
      union { unsigned u[4]; bf16x8 v; } pf;
      if (hi == 0) {
        pf.u[0] = pk[lh][s4 + 0]; pf.u[1] = pk[lh][s4 + 1];
        pf.u[2] = recv0;          pf.u[3] = recv1;
      } else {
        pf.u[0] = recv0;          pf.u[1] = recv1;
        pf.u[2] = pk[lh][s4 + 2]; pf.u[3] = pk[lh][s4 + 3];
      }
#pragma unroll
      for (int ds = 0; ds < 2; ++ds) {
        oacc[ds] = __builtin_amdgcn_mfma_f32_32x32x16_bf16(
            pf.v, vf[kc2 & 1][ds], oacc[ds], 0, 0, 0);
      }
    }
    kgb += 8192;
    vgb += 8192;
  }

  // ---- epilogue: store raw numerator + Z partial (no divide here)
  const float zrow = zacc + __shfl_xor(zacc, 32, 64);
  if (hi == 0)
    Zp[(size_t)split * Z_ELEMS + (size_t)(n0 + w * 32 + col) * NH + h] = zrow;

  float* onum = Onum + (size_t)split * ONUM_ELEMS;
#pragma unroll
  for (int ds = 0; ds < 2; ++ds) {
    const int d = ds * 32 + col;
#pragma unroll
    for (int r = 0; r < 16; ++r) {
      const int row = (r & 3) + 8 * (r >> 2) + 4 * hi;
      onum[((size_t)(n0 + w * 32 + row) * NH + h) * MD + d] = oacc[ds][r];
    }
  }
}

// ---------------- combine ----------------
__global__ __launch_bounds__(256) void diffattn_combine(
    const float* __restrict__ Onum, const float* __restrict__ Zp,
    float* __restrict__ Og, int nsplit) {
  const int idx = blockIdx.x * 256 + threadIdx.x;  // one float4 of output
  if (idx >= (int)(ONUM_ELEMS / 4)) return;
  const int nh = idx >> 4;
  const int d4 = (idx & 15) * 4;
  float z = 0.f;
  float4 o = make_float4(0.f, 0.f, 0.f, 0.f);
  for (int s = 0; s < nsplit; ++s) {
    z += Zp[(size_t)s * Z_ELEMS + nh];
    const float4 t = *(const float4*)(Onum + (size_t)s * ONUM_ELEMS +
                                      (size_t)nh * MD + d4);
    o.x += t.x; o.y += t.y; o.z += t.z; o.w += t.w;
  }
  const float zi = __builtin_amdgcn_rcpf(z);
  float4 r = make_float4(o.x * zi, o.y * zi, o.z * zi, o.w * zi);
  *(float4*)(Og + (size_t)nh * MD + d4) = r;
}

extern "C" void kernel_launch(void* const* d_in, const int* in_sizes, int n_in,
                              void* d_out, int out_size, void* d_ws, size_t ws_size,
                              hipStream_t stream) {
  const float* Q = (const float*)d_in[0];
  const float* K = (const float*)d_in[1];
  const float* V = (const float*)d_in[2];
  float* O = (float*)d_out;

  const size_t conv_bytes = (KB_ELEMS + VTB_ELEMS) * sizeof(unsigned short);
  int nsplit = 4;
  while (nsplit > 1 &&
         (size_t)nsplit * (ONUM_ELEMS + Z_ELEMS) * sizeof(float) + conv_bytes >
             ws_size)
    nsplit >>= 1;

  float* Onum = (float*)d_ws;
  float* Zp   = Onum + (size_t)nsplit * ONUM_ELEMS;
  unsigned short* Kbb = (unsigned short*)(Zp + (size_t)nsplit * Z_ELEMS);
  unsigned short* Vtb = Kbb + KB_ELEMS;

  const int lLen = NL / nsplit;
  diffattn_prepass<<<dim3(8 * (NL / 64)), dim3(256), 0, stream>>>(K, V, Kbb, Vtb);
  diffattn_partial<<<dim3(8 * 32 * nsplit), dim3(256), 0, stream>>>(
      Q, Kbb, Vtb, Onum, Zp, nsplit, lLen);
  diffattn_combine<<<dim3((ONUM_ELEMS / 4 + 255) / 256), dim3(256), 0, stream>>>(
      Onum, Zp, O, nsplit);
}

// Round 9
// 126.025 us; speedup vs baseline: 1.3996x; 1.3996x over previous
//
#include <hip/hip_runtime.h>
#include <stdint.h>

// DiffAttention: O[n,h,d] = sum_l sigmoid(q_n.k_l) v_l / sum_l sigmoid(q_n.k_l)
// N=L=4096, H=8, M=D=64, fp32 in/out, bf16 MFMA compute.
//
// R9 = R7 (LDS staging + single-barrier dbuf; R8 proved direct-global loads
// thrash L1 and expose L2 latency -> 107us) + two cuts:
//  (a) pi-permuted V layout: QK C/D-layout -> PV A-layout mismatch is a
//      bit2<->bit3 swap of l (involution). Prepass stores V's l bit-swapped;
//      PV A-frag = d1 regs [c*8..c*8+7] packed -> NO lane exchange at all.
//  (b) V-frag ds_reads hoisted ahead of the sigmoid so LDS reads overlap the
//      transcendental burst.
// Standing lessons: R3 never force 8 waves/EU (32-VGPR spill); R5 no
// __threadfence split-K (L2 writeback storm); R6 residency is register-capped
// at ~4 blocks/CU; R7 dbuf is latency-neutral (kept: 1 barrier/tile);
// SQ_LDS_BANK_CONFLICT==2^22 is b128 phase overhead, not fixable conflict.

typedef __bf16 bf16x8 __attribute__((ext_vector_type(8)));
typedef __bf16 bf16x2 __attribute__((ext_vector_type(2)));
typedef float  f32x2  __attribute__((ext_vector_type(2)));
typedef float  f32x16 __attribute__((ext_vector_type(16)));
typedef unsigned u32x4 __attribute__((ext_vector_type(4)));

constexpr int NH = 8, MD = 64, NL = 4096, NN = 4096;
constexpr size_t ONUM_ELEMS = (size_t)NN * NH * MD;  // per split
constexpr size_t Z_ELEMS    = (size_t)NN * NH;       // per split
constexpr size_t KB_ELEMS   = (size_t)NH * NL * MD;  // bf16
constexpr size_t VTB_ELEMS  = (size_t)NH * NL * MD;  // bf16

__device__ __forceinline__ unsigned packbf2(float a, float b) {
  bf16x2 t = __builtin_convertvector((f32x2){a, b}, bf16x2);
  return __builtin_bit_cast(unsigned, t);
}

__device__ __forceinline__ void glds16(const void* g, void* l) {
  __builtin_amdgcn_global_load_lds(
      (const __attribute__((address_space(1))) unsigned int*)g,
      (__attribute__((address_space(3))) unsigned int*)l, 16, 0, 0);
}

// ---------------- prepass: one block per (h, l-tile) ----------------
__global__ __launch_bounds__(256) void diffattn_prepass(
    const float* __restrict__ Kg, const float* __restrict__ Vg,
    unsigned short* __restrict__ Kb, unsigned short* __restrict__ Vtb) {
  __shared__ __attribute__((aligned(16))) unsigned short Vt_lds[64 * 64];
  const int tid = threadIdx.x;
  const int h = blockIdx.x & 7;
  const int t = blockIdx.x >> 3;

  // ---- K: [l][h][m] fp32 -> [h][l][m] bf16, 16B chunks swizzled by l&7
#pragma unroll
  for (int e = 0; e < 2; ++e) {
    const int g = tid * 2 + e;
    const int l = g >> 3, c = g & 7;
    const float* kp = Kg + (((size_t)(t * 64 + l) * NH + h) * MD) + c * 8;
    const float4 a = *(const float4*)kp;
    const float4 b = *(const float4*)(kp + 4);
    unsigned out[4] = {packbf2(a.x, a.y), packbf2(a.z, a.w),
                       packbf2(b.x, b.y), packbf2(b.z, b.w)};
    unsigned short* dst =
        Kb + ((size_t)h * NL + t * 64 + l) * MD + ((c ^ (l & 7)) * 8);
    *(uint4*)dst = *(const uint4*)out;
  }

  // ---- V: [l][h][d] fp32 -> LDS transpose (l bit2<->bit3 swapped: the
  //      pi-permutation that makes PV's A-frag equal QK's D regs) ->
  //      [h][t][d][p] bf16, 16B chunks swizzled by d&7
  {
    const int lr = tid & 63, dbase = (tid >> 6) * 16;
    // pi(l): swap bits 2 and 3 (involution)
    const int pl = (lr & 0x33) | ((lr & 4) << 1) | ((lr & 8) >> 1);
    const float* vp = Vg + (((size_t)(t * 64 + lr) * NH + h) * MD) + dbase;
#pragma unroll
    for (int i = 0; i < 4; ++i) {
      const float4 v = *(const float4*)(vp + i * 4);
      const int d0 = dbase + i * 4;
      Vt_lds[(d0 + 0) * 64 + pl] = __builtin_bit_cast(unsigned short, (__bf16)v.x);
      Vt_lds[(d0 + 1) * 64 + pl] = __builtin_bit_cast(unsigned short, (__bf16)v.y);
      Vt_lds[(d0 + 2) * 64 + pl] = __builtin_bit_cast(unsigned short, (__bf16)v.z);
      Vt_lds[(d0 + 3) * 64 + pl] = __builtin_bit_cast(unsigned short, (__bf16)v.w);
    }
  }
  __syncthreads();
#pragma unroll
  for (int e = 0; e < 2; ++e) {
    const int g = tid * 2 + e;
    const int d = g >> 3, cl = g & 7;
    const uint4 chunk = *(const uint4*)&Vt_lds[d * 64 + cl * 8];
    unsigned short* dst = Vtb + ((size_t)(h * 64 + t) * 64 + d) * 64 +
                          ((cl ^ (d & 7)) * 8);
    *(uint4*)dst = chunk;
  }
}

// ---------------- partial ----------------
__global__ __launch_bounds__(256, 4) void diffattn_partial(
    const float* __restrict__ Qg, const unsigned short* __restrict__ Kb,
    const unsigned short* __restrict__ Vtb, float* __restrict__ Onum,
    float* __restrict__ Zp, int nsplit, int lLen) {
  // double-buffered tiles: 2 x (8KB K + 8KB V) = 32KB
  __shared__ __attribute__((aligned(16))) unsigned short Ksh[2][64 * 64];
  __shared__ __attribute__((aligned(16))) unsigned short Vtsh[2][64 * 64];

  const int tid  = threadIdx.x;
  const int w    = tid >> 6;
  const int lane = tid & 63;
  const int col  = lane & 31;
  const int hi   = lane >> 5;

  const int h     = blockIdx.x & 7;
  const int tmp   = blockIdx.x >> 3;
  const int split = tmp % nsplit;
  const int n0    = (tmp / nsplit) * 128;
  const int lBeg  = split * lLen;

  // Q fragments (B operand), prescaled by -log2e: sigmoid = rcp(1+exp2(d1)).
  bf16x8 qf[4];
  {
    const float* qp = Qg + ((size_t)(n0 + w * 32 + col) * NH + h) * MD;
    const float c = -1.4426950408889634f;
#pragma unroll
    for (int kc = 0; kc < 4; ++kc) {
      const float4 x = *(const float4*)(qp + kc * 16 + hi * 8);
      const float4 y = *(const float4*)(qp + kc * 16 + hi * 8 + 4);
      bf16x8 f;
      f[0] = (__bf16)(c * x.x); f[1] = (__bf16)(c * x.y);
      f[2] = (__bf16)(c * x.z); f[3] = (__bf16)(c * x.w);
      f[4] = (__bf16)(c * y.x); f[5] = (__bf16)(c * y.y);
      f[6] = (__bf16)(c * y.z); f[7] = (__bf16)(c * y.w);
      qf[kc] = f;
    }
  }

  f32x16 oacc[2];
#pragma unroll
  for (int i = 0; i < 16; ++i) { oacc[0][i] = 0.f; oacc[1][i] = 0.f; }
  float zacc = 0.f;
  const f32x16 zf = {};  // zero C-operand for the first QK MFMA

  const char* kgh = (const char*)(Kb + (size_t)h * NL * MD);
  const char* vgh = (const char*)(Vtb + (size_t)h * NL * MD);
  const int o = w * 2048 + lane * 16;
  const int T = lLen >> 6;
  const int sw = col & 7;

  // prefetch tile 0 into buffer 0
  {
    const char* kgb = kgh + (size_t)lBeg * 128;
    const char* vgb = vgh + (size_t)lBeg * 128;
    glds16(kgb + o,        (char*)Ksh[0]  + w * 2048);
    glds16(kgb + o + 1024, (char*)Ksh[0]  + w * 2048 + 1024);
    glds16(vgb + o,        (char*)Vtsh[0] + w * 2048);
    glds16(vgb + o + 1024, (char*)Vtsh[0] + w * 2048 + 1024);
  }

  for (int t = 0; t < T; ++t) {
    const int cur = t & 1;
    // Single barrier/tile: per-wave vmcnt drain covers loads issued before
    // the PREVIOUS compute phase (cheap); barrier also separates buf reuse.
    __syncthreads();
    if (t + 1 < T) {  // prefetch t+1 into the other buffer
      const char* kgb = kgh + (size_t)(lBeg + (t + 1) * 64) * 128;
      const char* vgb = vgh + (size_t)(lBeg + (t + 1) * 64) * 128;
      glds16(kgb + o,        (char*)Ksh[cur ^ 1]  + w * 2048);
      glds16(kgb + o + 1024, (char*)Ksh[cur ^ 1]  + w * 2048 + 1024);
      glds16(vgb + o,        (char*)Vtsh[cur ^ 1] + w * 2048);
      glds16(vgb + o + 1024, (char*)Vtsh[cur ^ 1] + w * 2048 + 1024);
    }

    // ---- QK: D1[lh] (32 l x 32 q) = K(32l x 64k) x Qscaled(64k x 32q)
    f32x16 d1[2];
#pragma unroll
    for (int lh = 0; lh < 2; ++lh) {
      const int rowK = lh * 32 + col;
      const char* kp = (const char*)Ksh[cur] + rowK * 128;
      const int swk = rowK & 7;
      {
        const bf16x8 kf = *(const bf16x8*)(kp + ((hi ^ swk) * 16));
        d1[lh] = __builtin_amdgcn_mfma_f32_32x32x16_bf16(kf, qf[0], zf, 0, 0, 0);
      }
#pragma unroll
      for (int kc = 1; kc < 4; ++kc) {
        const bf16x8 kf = *(const bf16x8*)(kp + (((kc << 1) | hi) ^ swk) * 16);
        d1[lh] = __builtin_amdgcn_mfma_f32_32x32x16_bf16(kf, qf[kc], d1[lh], 0, 0, 0);
      }
    }

    // ---- V frag batch A (global chunks kc2=0,1) — in flight under sigmoid
    const char* vb = (const char*)Vtsh[cur];
    bf16x8 vfA[2][2];
#pragma unroll
    for (int c = 0; c < 2; ++c)
#pragma unroll
      for (int ds = 0; ds < 2; ++ds) {
        const int rowV = ds * 32 + col;
        vfA[c][ds] = *(const bf16x8*)(vb + rowV * 128 +
                                      (((c << 1) | hi) ^ (rowV & 7)) * 16);
      }

    // ---- sigmoid + Z accumulate + pack pairs (reg order == pi-order)
    unsigned pk[2][8];
#pragma unroll
    for (int lh = 0; lh < 2; ++lh) {
      float s[16];
#pragma unroll
      for (int r = 0; r < 16; ++r) {
        const float e = __builtin_amdgcn_exp2f(d1[lh][r]);
        s[r] = __builtin_amdgcn_rcpf(1.0f + e);
        zacc += s[r];
      }
#pragma unroll
      for (int p = 0; p < 8; ++p) pk[lh][p] = packbf2(s[2 * p], s[2 * p + 1]);
    }

    // ---- PV: O += P x V(pi-ordered). A-frag = pk[lh] dwords [c*4..c*4+3].
#pragma unroll
    for (int c = 0; c < 2; ++c) {
      const bf16x8 pf =
          __builtin_bit_cast(bf16x8, *(const u32x4*)&pk[0][c * 4]);
#pragma unroll
      for (int ds = 0; ds < 2; ++ds)
        oacc[ds] = __builtin_amdgcn_mfma_f32_32x32x16_bf16(pf, vfA[c][ds],
                                                           oacc[ds], 0, 0, 0);
    }
    // ---- V frag batch B (global chunks kc2=2,3), reuse vfA regs
#pragma unroll
    for (int c = 0; c < 2; ++c)
#pragma unroll
      for (int ds = 0; ds < 2; ++ds) {
        const int rowV = ds * 32 + col;
        vfA[c][ds] = *(const bf16x8*)(vb + rowV * 128 +
                                      ((((c + 2) << 1 | hi)) ^ (rowV & 7)) * 16);
      }
#pragma unroll
    for (int c = 0; c < 2; ++c) {
      const bf16x8 pf =
          __builtin_bit_cast(bf16x8, *(const u32x4*)&pk[1][c * 4]);
#pragma unroll
      for (int ds = 0; ds < 2; ++ds)
        oacc[ds] = __builtin_amdgcn_mfma_f32_32x32x16_bf16(pf, vfA[c][ds],
                                                           oacc[ds], 0, 0, 0);
    }
  }

  // ---- epilogue: store raw numerator + Z partial (no divide here)
  const float zrow = zacc + __shfl_xor(zacc, 32, 64);
  if (hi == 0)
    Zp[(size_t)split * Z_ELEMS + (size_t)(n0 + w * 32 + col) * NH + h] = zrow;

  float* onum = Onum + (size_t)split * ONUM_ELEMS;
#pragma unroll
  for (int ds = 0; ds < 2; ++ds) {
    const int d = ds * 32 + col;
#pragma unroll
    for (int r = 0; r < 16; ++r) {
      const int row = (r & 3) + 8 * (r >> 2) + 4 * hi;
      onum[((size_t)(n0 + w * 32 + row) * NH + h) * MD + d] = oacc[ds][r];
    }
  }
}

// ---------------- combine ----------------
__global__ __launch_bounds__(256) void diffattn_combine(
    const float* __restrict__ Onum, const float* __restrict__ Zp,
    float* __restrict__ Og, int nsplit) {
  const int idx = blockIdx.x * 256 + threadIdx.x;  // one float4 of output
  if (idx >= (int)(ONUM_ELEMS / 4)) return;
  const int nh = idx >> 4;
  const int d4 = (idx & 15) * 4;
  float z = 0.f;
  float4 o = make_float4(0.f, 0.f, 0.f, 0.f);
  for (int s = 0; s < nsplit; ++s) {
    z += Zp[(size_t)s * Z_ELEMS + nh];
    const float4 t = *(const float4*)(Onum + (size_t)s * ONUM_ELEMS +
                                      (size_t)nh * MD + d4);
    o.x += t.x; o.y += t.y; o.z += t.z; o.w += t.w;
  }
  const float zi = __builtin_amdgcn_rcpf(z);
  float4 r = make_float4(o.x * zi, o.y * zi, o.z * zi, o.w * zi);
  *(float4*)(Og + (size_t)nh * MD + d4) = r;
}

extern "C" void kernel_launch(void* const* d_in, const int* in_sizes, int n_in,
                              void* d_out, int out_size, void* d_ws, size_t ws_size,
                              hipStream_t stream) {
  const float* Q = (const float*)d_in[0];
  const float* K = (const float*)d_in[1];
  const float* V = (const float*)d_in[2];
  float* O = (float*)d_out;

  const size_t conv_bytes = (KB_ELEMS + VTB_ELEMS) * sizeof(unsigned short);
  int nsplit = 4;
  while (nsplit > 1 &&
         (size_t)nsplit * (ONUM_ELEMS + Z_ELEMS) * sizeof(float) + conv_bytes >
             ws_size)
    nsplit >>= 1;

  float* Onum = (float*)d_ws;
  float* Zp   = Onum + (size_t)nsplit * ONUM_ELEMS;
  unsigned short* Kbb = (unsigned short*)(Zp + (size_t)nsplit * Z_ELEMS);
  unsigned short* Vtb = Kbb + KB_ELEMS;

  const int lLen = NL / nsplit;
  diffattn_prepass<<<dim3(8 * (NL / 64)), dim3(256), 0, stream>>>(K, V, Kbb, Vtb);
  diffattn_partial<<<dim3(8 * 32 * nsplit), dim3(256), 0, stream>>>(
      Q, Kbb, Vtb, Onum, Zp, nsplit, lLen);
  diffattn_combine<<<dim3((ONUM_ELEMS / 4 + 255) / 256), dim3(256), 0, stream>>>(
      Onum, Zp, O, nsplit);
}